// Round 5
// baseline (298.316 us; speedup 1.0000x reference)
//
#include <hip/hip_runtime.h>
#include <math.h>

#define NNODES 40000
#define CCH    128
#define NH     8
#define HD     16
#define NEDGE  640000
#define NBLK   157    // ceil(NNODES/256)
#define FBLK   10000  // k_fused blocks (4 waves each -> 40000 nodes)

typedef __attribute__((ext_vector_type(8))) short bf16x8;
typedef __attribute__((ext_vector_type(4))) float f32x4;

__device__ inline unsigned short f2bf(float f) {
  union { float f; unsigned u; } c; c.f = f;
  unsigned r = c.u + 0x7fffu + ((c.u >> 16) & 1u);
  return (unsigned short)(r >> 16);
}
__device__ inline float bflo(unsigned u) { union { unsigned i; float f; } c; c.i = u << 16; return c.f; }
__device__ inline float bfhi(unsigned u) { union { unsigned i; float f; } c; c.i = u & 0xffff0000u; return c.f; }

// ---------------- LayerNorm: 4 waves/block, 1 row/wave, bf16 out ----------
__global__ __launch_bounds__(256) void k_ln_bf(const float* __restrict__ x,
                                               const float* __restrict__ g,
                                               const float* __restrict__ b,
                                               unsigned* __restrict__ out) {
  int wave = threadIdx.x >> 6;
  int lane = threadIdx.x & 63;
  int row  = blockIdx.x * 4 + wave;
  if (row >= NNODES) return;
  const float2* xr = (const float2*)(x + (size_t)row * CCH);
  float2 v = xr[lane];
  float s  = v.x + v.y;
  float ss = v.x * v.x + v.y * v.y;
  #pragma unroll
  for (int d = 1; d < 64; d <<= 1) {
    s  += __shfl_xor(s, d);
    ss += __shfl_xor(ss, d);
  }
  float mean = s * (1.0f / CCH);
  float var  = ss * (1.0f / CCH) - mean * mean;
  float rstd = rsqrtf(var + 1e-5f);
  float2 gg = ((const float2*)g)[lane];
  float2 bb = ((const float2*)b)[lane];
  float ox = (v.x - mean) * rstd * gg.x + bb.x;
  float oy = (v.y - mean) * rstd * gg.y + bb.y;
  out[(size_t)row * 64 + lane] = ((unsigned)f2bf(oy) << 16) | f2bf(ox);
}

// ---------------- Weight prep: transpose + bf16 convert -------------------
__global__ __launch_bounds__(256) void k_wprep(const float* __restrict__ W,
                                               unsigned short* __restrict__ Wt,
                                               int K, int Nc) {
  int idx = blockIdx.x * 256 + threadIdx.x;
  if (idx >= K * Nc) return;
  int n = idx / K, k = idx - n * K;
  Wt[idx] = f2bf(W[(size_t)k * Nc + n]);
}

__global__ __launch_bounds__(256) void k_bcat(const float* __restrict__ bq,
                                              const float* __restrict__ bk,
                                              const float* __restrict__ bv,
                                              float* __restrict__ bqkv) {
  int t = threadIdx.x + blockIdx.x * 256;
  if (t < 128)      bqkv[t] = bq[t];
  else if (t < 256) bqkv[t] = bk[t - 128];
  else if (t < 384) bqkv[t] = bv[t - 256];
}

// ---------------- MFMA GEMM: out = [res +] A@W + bias [,relu] -------------
template <bool RELU, bool RES, bool OUTBF>
__global__ __launch_bounds__(256) void k_mgemm(const unsigned short* __restrict__ A,
                                               const unsigned short* __restrict__ Bt,
                                               const float* __restrict__ bias,
                                               const float* __restrict__ res,
                                               void* __restrict__ outp,
                                               int K, int Nc) {
  __shared__ unsigned short As[64 * 64];
  __shared__ unsigned short Bs[128 * 64];
  const int tid  = threadIdx.x;
  const int row0 = blockIdx.x * 64;
  const int c0   = blockIdx.y * 128;
  const int l    = tid & 63;
  const int w    = tid >> 6;
  const int wr   = w >> 1;
  const int wc   = w & 1;

  f32x4 acc[2][4] = {};

  for (int kc = 0; kc < K; kc += 64) {
    __syncthreads();
    #pragma unroll
    for (int it = 0; it < 2; it++) {
      int idx = it * 256 + tid;
      int r = idx >> 3, s = idx & 7;
      uint4 vv = *(const uint4*)(A + (size_t)(row0 + r) * K + kc + s * 8);
      *(uint4*)(As + r * 64 + ((s ^ (r & 7)) * 8)) = vv;
    }
    #pragma unroll
    for (int it = 0; it < 4; it++) {
      int idx = it * 256 + tid;
      int n = idx >> 3, s = idx & 7;
      uint4 vv = *(const uint4*)(Bt + (size_t)(c0 + n) * K + kc + s * 8);
      *(uint4*)(Bs + n * 64 + ((s ^ (n & 7)) * 8)) = vv;
    }
    __syncthreads();
    #pragma unroll
    for (int kk = 0; kk < 2; kk++) {
      int sb = kk * 4 + (l >> 4);
      bf16x8 af[2], bfr[4];
      #pragma unroll
      for (int mi = 0; mi < 2; mi++) {
        int r = wr * 32 + mi * 16 + (l & 15);
        af[mi] = *(const bf16x8*)(As + r * 64 + ((sb ^ (r & 7)) * 8));
      }
      #pragma unroll
      for (int ni = 0; ni < 4; ni++) {
        int n = wc * 64 + ni * 16 + (l & 15);
        bfr[ni] = *(const bf16x8*)(Bs + n * 64 + ((sb ^ (n & 7)) * 8));
      }
      #pragma unroll
      for (int mi = 0; mi < 2; mi++)
        #pragma unroll
        for (int ni = 0; ni < 4; ni++)
          acc[mi][ni] = __builtin_amdgcn_mfma_f32_16x16x32_bf16(af[mi], bfr[ni], acc[mi][ni], 0, 0, 0);
    }
  }

  #pragma unroll
  for (int mi = 0; mi < 2; mi++) {
    #pragma unroll
    for (int p = 0; p < 4; p++) {
      int r = row0 + wr * 32 + mi * 16 + (l >> 4) * 4 + p;
      #pragma unroll
      for (int ni = 0; ni < 4; ni++) {
        int c = c0 + wc * 64 + ni * 16 + (l & 15);
        float val = acc[mi][ni][p] + bias[c];
        if (RES)  val += res[(size_t)r * Nc + c];
        if (RELU) val = fmaxf(val, 0.f);
        if (OUTBF) ((unsigned short*)outp)[(size_t)r * Nc + c] = f2bf(val);
        else       ((float*)outp)[(size_t)r * Nc + c] = val;
      }
    }
  }
}

// ---------------- CSR build: histogram -> 3-stage scan -> scatter ----------
__global__ __launch_bounds__(256) void k_hist(const int* __restrict__ ei,
                                              int* __restrict__ deg) {
  int e = blockIdx.x * 256 + threadIdx.x;
  if (e >= NEDGE) return;
  atomicAdd(&deg[ei[NEDGE + e]], 1);
}

__global__ __launch_bounds__(256) void k_scan3a(const int* __restrict__ deg,
                                                int* __restrict__ bsum) {
  int i = blockIdx.x * 256 + threadIdx.x;
  int d = (i < NNODES) ? deg[i] : 0;
  #pragma unroll
  for (int s = 1; s < 64; s <<= 1) d += __shfl_xor(d, s);
  __shared__ int ws4[4];
  if ((threadIdx.x & 63) == 0) ws4[threadIdx.x >> 6] = d;
  __syncthreads();
  if (threadIdx.x == 0) bsum[blockIdx.x] = ws4[0] + ws4[1] + ws4[2] + ws4[3];
}

__global__ __launch_bounds__(256) void k_scan3b(const int* __restrict__ bsum,
                                                int* __restrict__ bpre) {
  int t = threadIdx.x;
  int d = (t < NBLK) ? bsum[t] : 0;
  int lane = t & 63, wv = t >> 6;
  int incl = d;
  #pragma unroll
  for (int s = 1; s < 64; s <<= 1) { int o = __shfl_up(incl, s); if (lane >= s) incl += o; }
  __shared__ int wsum[4];
  if (lane == 63) wsum[wv] = incl;
  __syncthreads();
  int base = 0;
  for (int w2 = 0; w2 < wv; w2++) base += wsum[w2];
  if (t < NBLK) bpre[t] = base + incl - d;
}

__global__ __launch_bounds__(256) void k_scan3c(const int* __restrict__ deg,
                                                const int* __restrict__ bpre,
                                                int* __restrict__ off,
                                                int* __restrict__ cursor) {
  int t = threadIdx.x;
  int i = blockIdx.x * 256 + t;
  int d = (i < NNODES) ? deg[i] : 0;
  int lane = t & 63, wv = t >> 6;
  int incl = d;
  #pragma unroll
  for (int s = 1; s < 64; s <<= 1) { int o = __shfl_up(incl, s); if (lane >= s) incl += o; }
  __shared__ int wsum[4];
  if (lane == 63) wsum[wv] = incl;
  __syncthreads();
  int base = bpre[blockIdx.x];
  for (int w2 = 0; w2 < wv; w2++) base += wsum[w2];
  int ex = base + incl - d;
  if (i < NNODES) { off[i] = ex; cursor[i] = ex; }
  if (i == 0) off[NNODES] = NEDGE;
}

__global__ __launch_bounds__(256) void k_scatter(const int* __restrict__ ei,
                                                 int* __restrict__ cursor,
                                                 int* __restrict__ srcs) {
  int e = blockIdx.x * 256 + threadIdx.x;
  if (e >= NEDGE) return;
  int src = ei[e];
  int dst = ei[NEDGE + e];
  int pos = atomicAdd(&cursor[dst], 1);
  srcs[pos] = src;
}

// ------- Fused scores + aggregation: 1 wave per dst node -------------------
// qkv packed [N][384]: q 0..127, k 128..255, v 256..383.
// U_n = sum_e exp(q_n . k_src / 4) * v_src  (unnormalized), per-head partial
// denominators -> hpart[block*8+h].
__global__ __launch_bounds__(256) void k_fused(const unsigned short* __restrict__ qkv,
                                               const int* __restrict__ off,
                                               const int* __restrict__ srcs,
                                               unsigned* __restrict__ U,
                                               float* __restrict__ hpart) {
  const int wave = threadIdx.x >> 6;
  const int lane = threadIdx.x & 63;
  const int n = blockIdx.x * 4 + wave;
  const int g   = lane >> 4;   // edge sub-group 0..3
  const int c16 = lane & 15;   // channel group (8 channels)

  // q row fragment for this lane's 8 channels
  uint4 qv = *(const uint4*)(qkv + (size_t)n * 384 + c16 * 8);
  float q0 = bflo(qv.x), q1 = bfhi(qv.x), q2 = bflo(qv.y), q3 = bfhi(qv.y);
  float q4 = bflo(qv.z), q5 = bfhi(qv.z), q6 = bflo(qv.w), q7 = bfhi(qv.w);

  float a0 = 0.f, a1 = 0.f, a2 = 0.f, a3 = 0.f, a4 = 0.f, a5 = 0.f, a6 = 0.f, a7 = 0.f;
  float lsum = 0.f;
  int i0 = off[n], i1 = off[n + 1];
  for (int i = i0; i < i1; i += 64) {
    int s_l = (i + lane < i1) ? srcs[i + lane] : 0;
    int cnt = i1 - i; if (cnt > 64) cnt = 64;
    for (int j = 0; j < cnt; j += 4) {
      int src = __shfl(s_l, j + g);
      bool valid = (j + g < cnt);
      const unsigned short* kr = qkv + (size_t)src * 384 + 128 + c16 * 8;
      uint4 kv = *(const uint4*)kr;
      uint4 vv = *(const uint4*)(kr + 128);
      float p = q0 * bflo(kv.x) + q1 * bfhi(kv.x) + q2 * bflo(kv.y) + q3 * bfhi(kv.y)
              + q4 * bflo(kv.z) + q5 * bfhi(kv.z) + q6 * bflo(kv.w) + q7 * bfhi(kv.w);
      p += __shfl_xor(p, 1);                  // pair within head
      float w = valid ? __expf(p * 0.25f) : 0.f;
      lsum += w;
      a0 += w * bflo(vv.x); a1 += w * bfhi(vv.x);
      a2 += w * bflo(vv.y); a3 += w * bfhi(vv.y);
      a4 += w * bflo(vv.z); a5 += w * bfhi(vv.z);
      a6 += w * bflo(vv.w); a7 += w * bfhi(vv.w);
    }
  }
  // fold the 4 edge-groups (bits 4,5). lsum: each edge lives in exactly one g;
  // lanes 2h,2h+1 hold identical per-g sums, so after folding g the value at
  // any lane with c16=2h (or 2h+1) is the per-(node,head) denominator partial.
  #pragma unroll
  for (int d = 16; d < 64; d <<= 1) {
    a0 += __shfl_xor(a0, d); a1 += __shfl_xor(a1, d);
    a2 += __shfl_xor(a2, d); a3 += __shfl_xor(a3, d);
    a4 += __shfl_xor(a4, d); a5 += __shfl_xor(a5, d);
    a6 += __shfl_xor(a6, d); a7 += __shfl_xor(a7, d);
    lsum += __shfl_xor(lsum, d);
  }
  __shared__ float wsum[4][8];
  if (lane < 16) {
    if ((c16 & 1) == 0) wsum[wave][c16 >> 1] = lsum;
    uint4 o;
    o.x = ((unsigned)f2bf(a1) << 16) | f2bf(a0);
    o.y = ((unsigned)f2bf(a3) << 16) | f2bf(a2);
    o.z = ((unsigned)f2bf(a5) << 16) | f2bf(a4);
    o.w = ((unsigned)f2bf(a7) << 16) | f2bf(a6);
    *(uint4*)(U + (size_t)n * 64 + c16 * 4) = o;
  }
  __syncthreads();
  if (threadIdx.x < 8) {
    hpart[blockIdx.x * 8 + threadIdx.x] =
        wsum[0][threadIdx.x] + wsum[1][threadIdx.x] + wsum[2][threadIdx.x] + wsum[3][threadIdx.x];
  }
}

__global__ __launch_bounds__(256) void k_reduce_inv(const float* __restrict__ hpart,
                                                    float* __restrict__ inv) {
  const int tid = threadIdx.x;
  const int h = tid & 7;
  float s = 0.f;
  for (int i = tid >> 3; i < FBLK; i += 32) s += hpart[i * 8 + h];
  #pragma unroll
  for (int d = 8; d < 64; d <<= 1) s += __shfl_xor(s, d);
  __shared__ float wsum[4][8];
  int lane = tid & 63, wv = tid >> 6;
  if (lane < 8) wsum[wv][lane] = s;
  __syncthreads();
  if (tid < 8) {
    float t = wsum[0][tid] + wsum[1][tid] + wsum[2][tid] + wsum[3][tid];
    inv[tid] = 1.0f / t;
  }
}

// ---------------- Scale U by inv[head] (in place, bf16) -------------------
__global__ __launch_bounds__(256) void k_scale(unsigned* __restrict__ U,
                                               const float* __restrict__ inv) {
  __shared__ float sinv[8];
  if (threadIdx.x < 8) sinv[threadIdx.x] = inv[threadIdx.x];
  __syncthreads();
  const int total = NNODES * 64;
  for (int i = blockIdx.x * 256 + threadIdx.x; i < total; i += 2048 * 256) {
    unsigned u = U[i];
    float s = sinv[(i & 63) >> 3];
    U[i] = ((unsigned)f2bf(bfhi(u) * s) << 16) | f2bf(bflo(u) * s);
  }
}

extern "C" void kernel_launch(void* const* d_in, const int* in_sizes, int n_in,
                              void* d_out, int out_size, void* d_ws, size_t ws_size,
                              hipStream_t stream) {
  const float* x    = (const float*)d_in[0];
  const int*   ei   = (const int*)d_in[1];
  const float* Wq   = (const float*)d_in[2];
  const float* bq   = (const float*)d_in[3];
  const float* Wk   = (const float*)d_in[4];
  const float* bk   = (const float*)d_in[5];
  const float* Wv   = (const float*)d_in[6];
  const float* bv   = (const float*)d_in[7];
  const float* Wo   = (const float*)d_in[8];
  const float* bo   = (const float*)d_in[9];
  const float* ln1g = (const float*)d_in[10];
  const float* ln1b = (const float*)d_in[11];
  const float* ln2g = (const float*)d_in[12];
  const float* ln2b = (const float*)d_in[13];
  const float* W1   = (const float*)d_in[14];
  const float* b1   = (const float*)d_in[15];
  const float* W2   = (const float*)d_in[16];
  const float* b2   = (const float*)d_in[17];
  float* out = (float*)d_out;

  char* base = (char*)d_ws;
  const size_t NCb = (size_t)NNODES * CCH * 2;                 // 10.24 MB
  unsigned short* xn   = (unsigned short*)(base);              // 10.24 MB; later xn2
  unsigned short* qkv  = (unsigned short*)(base + NCb);        // [N][384] 30.72 MB
  unsigned short* agg  = (unsigned short*)(base + 4 * NCb);    // U [N][128] 10.24 MB
  float*          x1   = (float*)(base + 5 * NCb);             // 20.48 MB
  unsigned short* ffn1 = qkv;                                  // overlays qkv+agg (40.96 MB)
  char* aux = base + 5 * NCb + (size_t)NNODES * CCH * 4;
  int* deg    = (int*)aux;                     aux += (size_t)NNODES * 4 + 256;
  int* off    = (int*)aux;                     aux += (size_t)(NNODES + 1) * 4 + 256;
  int* cursor = (int*)aux;                     aux += (size_t)NNODES * 4 + 256;
  int* srcs   = (int*)aux;                     aux += (size_t)NEDGE * 4;
  int* bsum   = (int*)aux;                     aux += 256 * 4;
  int* bpre   = (int*)aux;                     aux += 256 * 4;
  float* hpart = (float*)aux;                  aux += (size_t)FBLK * 8 * 4;
  float* inv   = (float*)aux;                  aux += 256;
  float* bqkv  = (float*)aux;                  aux += 384 * 4 + 256;
  unsigned short* Wqkvt = (unsigned short*)aux; aux += (size_t)384 * CCH * 2;
  unsigned short* Wot  = (unsigned short*)aux; aux += (size_t)CCH * CCH * 2;
  unsigned short* W1t  = (unsigned short*)aux; aux += (size_t)CCH * 4 * CCH * 2;
  unsigned short* W2t  = (unsigned short*)aux; aux += (size_t)CCH * 4 * CCH * 2;
  unsigned short* xn2 = xn;

  dim3 blk(256);
  dim3 gLN(NNODES / 4);
  dim3 gM(NNODES / 64, 1);
  dim3 gM3(NNODES / 64, 3);
  dim3 gM4(NNODES / 64, 4);
  dim3 gE((NEDGE + 255) / 256);
  dim3 gW64((CCH * CCH + 255) / 256);
  dim3 gW256((CCH * 4 * CCH + 255) / 256);

  // CSR build (depends only on ei)
  hipMemsetAsync(deg, 0, (size_t)NNODES * 4, stream);
  k_hist<<<gE, blk, 0, stream>>>(ei, deg);
  k_scan3a<<<NBLK, blk, 0, stream>>>(deg, bsum);
  k_scan3b<<<1, blk, 0, stream>>>(bsum, bpre);
  k_scan3c<<<NBLK, blk, 0, stream>>>(deg, bpre, off, cursor);
  k_scatter<<<gE, blk, 0, stream>>>(ei, cursor, srcs);

  // weight prep: Wqkv_t = [Wq^T | Wk^T | Wv^T] rows, bf16
  k_wprep<<<gW64, blk, 0, stream>>>(Wq, Wqkvt, CCH, CCH);
  k_wprep<<<gW64, blk, 0, stream>>>(Wk, Wqkvt + (size_t)CCH * CCH, CCH, CCH);
  k_wprep<<<gW64, blk, 0, stream>>>(Wv, Wqkvt + (size_t)2 * CCH * CCH, CCH, CCH);
  k_wprep<<<gW64, blk, 0, stream>>>(Wo, Wot, CCH, CCH);
  k_wprep<<<gW256, blk, 0, stream>>>(W1, W1t, CCH, 4 * CCH);
  k_wprep<<<gW256, blk, 0, stream>>>(W2, W2t, 4 * CCH, CCH);
  k_bcat<<<2, blk, 0, stream>>>(bq, bk, bv, bqkv);

  // LN1 + packed QKV GEMM
  k_ln_bf<<<gLN, blk, 0, stream>>>(x, ln1g, ln1b, (unsigned*)xn);
  k_mgemm<false, false, true><<<gM3, blk, 0, stream>>>(xn, Wqkvt, bqkv, nullptr, qkv, CCH, 384);

  // fused scores + aggregation (unnormalized) + denominator partials
  k_fused<<<FBLK, blk, 0, stream>>>(qkv, off, srcs, (unsigned*)agg, hpart);
  k_reduce_inv<<<1, blk, 0, stream>>>(hpart, inv);
  k_scale<<<2048, blk, 0, stream>>>((unsigned*)agg, inv);

  // out-proj + residual -> x1 (fp32)
  k_mgemm<false, true, false><<<gM, blk, 0, stream>>>(agg, Wot, bo, x, x1, CCH, CCH);
  // LN2 -> xn2 (overlays xn)
  k_ln_bf<<<gLN, blk, 0, stream>>>(x1, ln2g, ln2b, (unsigned*)xn2);
  // FFN1 (relu, bf16 out, overlays qkv+agg)
  k_mgemm<true, false, true><<<gM4, blk, 0, stream>>>(xn2, W1t, b1, nullptr, ffn1, CCH, 4 * CCH);
  // FFN2 (+residual x1) -> d_out fp32
  k_mgemm<false, true, false><<<gM, blk, 0, stream>>>(ffn1, W2t, b2, x1, out, 4 * CCH, CCH);
}

// Round 6
// 225.592 us; speedup vs baseline: 1.3224x; 1.3224x over previous
//
#include <hip/hip_runtime.h>
#include <math.h>

#define NNODES 40000
#define CCH    128
#define NH     8
#define HD     16
#define NEDGE  640000
#define NBLK   157    // ceil(NNODES/256)
#define FBLK   10000  // k_fused blocks (4 waves each -> 40000 nodes)
#define RBLK   40     // k_reduce_part blocks (250 hpart rows each)

typedef __attribute__((ext_vector_type(8))) short bf16x8;
typedef __attribute__((ext_vector_type(4))) float f32x4;

__device__ inline unsigned short f2bf(float f) {
  union { float f; unsigned u; } c; c.f = f;
  unsigned r = c.u + 0x7fffu + ((c.u >> 16) & 1u);
  return (unsigned short)(r >> 16);
}
__device__ inline float bflo(unsigned u) { union { unsigned i; float f; } c; c.i = u << 16; return c.f; }
__device__ inline float bfhi(unsigned u) { union { unsigned i; float f; } c; c.i = u & 0xffff0000u; return c.f; }

// ---------------- LayerNorm: 4 waves/block, 1 row/wave, bf16 out ----------
__global__ __launch_bounds__(256) void k_ln_bf(const float* __restrict__ x,
                                               const float* __restrict__ g,
                                               const float* __restrict__ b,
                                               unsigned* __restrict__ out) {
  int wave = threadIdx.x >> 6;
  int lane = threadIdx.x & 63;
  int row  = blockIdx.x * 4 + wave;
  if (row >= NNODES) return;
  const float2* xr = (const float2*)(x + (size_t)row * CCH);
  float2 v = xr[lane];
  float s  = v.x + v.y;
  float ss = v.x * v.x + v.y * v.y;
  #pragma unroll
  for (int d = 1; d < 64; d <<= 1) {
    s  += __shfl_xor(s, d);
    ss += __shfl_xor(ss, d);
  }
  float mean = s * (1.0f / CCH);
  float var  = ss * (1.0f / CCH) - mean * mean;
  float rstd = rsqrtf(var + 1e-5f);
  float2 gg = ((const float2*)g)[lane];
  float2 bb = ((const float2*)b)[lane];
  float ox = (v.x - mean) * rstd * gg.x + bb.x;
  float oy = (v.y - mean) * rstd * gg.y + bb.y;
  out[(size_t)row * 64 + lane] = ((unsigned)f2bf(oy) << 16) | f2bf(ox);
}

// ---------------- Weight prep: transpose + bf16 convert -------------------
__global__ __launch_bounds__(256) void k_wprep(const float* __restrict__ W,
                                               unsigned short* __restrict__ Wt,
                                               int K, int Nc) {
  int idx = blockIdx.x * 256 + threadIdx.x;
  if (idx >= K * Nc) return;
  int n = idx / K, k = idx - n * K;
  Wt[idx] = f2bf(W[(size_t)k * Nc + n]);
}

__global__ __launch_bounds__(256) void k_bcat(const float* __restrict__ bq,
                                              const float* __restrict__ bk,
                                              const float* __restrict__ bv,
                                              float* __restrict__ bqkv) {
  int t = threadIdx.x + blockIdx.x * 256;
  if (t < 128)      bqkv[t] = bq[t];
  else if (t < 256) bqkv[t] = bk[t - 128];
  else if (t < 384) bqkv[t] = bv[t - 256];
}

// ---------------- MFMA GEMM: out = [res +] A@W + bias [,relu] -------------
template <bool RELU, bool RES, bool OUTBF>
__global__ __launch_bounds__(256) void k_mgemm(const unsigned short* __restrict__ A,
                                               const unsigned short* __restrict__ Bt,
                                               const float* __restrict__ bias,
                                               const float* __restrict__ res,
                                               void* __restrict__ outp,
                                               int K, int Nc) {
  __shared__ unsigned short As[64 * 64];
  __shared__ unsigned short Bs[128 * 64];
  const int tid  = threadIdx.x;
  const int row0 = blockIdx.x * 64;
  const int c0   = blockIdx.y * 128;
  const int l    = tid & 63;
  const int w    = tid >> 6;
  const int wr   = w >> 1;
  const int wc   = w & 1;

  f32x4 acc[2][4] = {};

  for (int kc = 0; kc < K; kc += 64) {
    __syncthreads();
    #pragma unroll
    for (int it = 0; it < 2; it++) {
      int idx = it * 256 + tid;
      int r = idx >> 3, s = idx & 7;
      uint4 vv = *(const uint4*)(A + (size_t)(row0 + r) * K + kc + s * 8);
      *(uint4*)(As + r * 64 + ((s ^ (r & 7)) * 8)) = vv;
    }
    #pragma unroll
    for (int it = 0; it < 4; it++) {
      int idx = it * 256 + tid;
      int n = idx >> 3, s = idx & 7;
      uint4 vv = *(const uint4*)(Bt + (size_t)(c0 + n) * K + kc + s * 8);
      *(uint4*)(Bs + n * 64 + ((s ^ (n & 7)) * 8)) = vv;
    }
    __syncthreads();
    #pragma unroll
    for (int kk = 0; kk < 2; kk++) {
      int sb = kk * 4 + (l >> 4);
      bf16x8 af[2], bfr[4];
      #pragma unroll
      for (int mi = 0; mi < 2; mi++) {
        int r = wr * 32 + mi * 16 + (l & 15);
        af[mi] = *(const bf16x8*)(As + r * 64 + ((sb ^ (r & 7)) * 8));
      }
      #pragma unroll
      for (int ni = 0; ni < 4; ni++) {
        int n = wc * 64 + ni * 16 + (l & 15);
        bfr[ni] = *(const bf16x8*)(Bs + n * 64 + ((sb ^ (n & 7)) * 8));
      }
      #pragma unroll
      for (int mi = 0; mi < 2; mi++)
        #pragma unroll
        for (int ni = 0; ni < 4; ni++)
          acc[mi][ni] = __builtin_amdgcn_mfma_f32_16x16x32_bf16(af[mi], bfr[ni], acc[mi][ni], 0, 0, 0);
    }
  }

  #pragma unroll
  for (int mi = 0; mi < 2; mi++) {
    #pragma unroll
    for (int p = 0; p < 4; p++) {
      int r = row0 + wr * 32 + mi * 16 + (l >> 4) * 4 + p;
      #pragma unroll
      for (int ni = 0; ni < 4; ni++) {
        int c = c0 + wc * 64 + ni * 16 + (l & 15);
        float val = acc[mi][ni][p] + bias[c];
        if (RES)  val += res[(size_t)r * Nc + c];
        if (RELU) val = fmaxf(val, 0.f);
        if (OUTBF) ((unsigned short*)outp)[(size_t)r * Nc + c] = f2bf(val);
        else       ((float*)outp)[(size_t)r * Nc + c] = val;
      }
    }
  }
}

// ---------------- CSR build: histogram -> 3-stage scan -> scatter ----------
__global__ __launch_bounds__(256) void k_hist(const int* __restrict__ ei,
                                              int* __restrict__ deg) {
  int e = blockIdx.x * 256 + threadIdx.x;
  if (e >= NEDGE) return;
  atomicAdd(&deg[ei[NEDGE + e]], 1);
}

__global__ __launch_bounds__(256) void k_scan3a(const int* __restrict__ deg,
                                                int* __restrict__ bsum) {
  int i = blockIdx.x * 256 + threadIdx.x;
  int d = (i < NNODES) ? deg[i] : 0;
  #pragma unroll
  for (int s = 1; s < 64; s <<= 1) d += __shfl_xor(d, s);
  __shared__ int ws4[4];
  if ((threadIdx.x & 63) == 0) ws4[threadIdx.x >> 6] = d;
  __syncthreads();
  if (threadIdx.x == 0) bsum[blockIdx.x] = ws4[0] + ws4[1] + ws4[2] + ws4[3];
}

__global__ __launch_bounds__(256) void k_scan3b(const int* __restrict__ bsum,
                                                int* __restrict__ bpre) {
  int t = threadIdx.x;
  int d = (t < NBLK) ? bsum[t] : 0;
  int lane = t & 63, wv = t >> 6;
  int incl = d;
  #pragma unroll
  for (int s = 1; s < 64; s <<= 1) { int o = __shfl_up(incl, s); if (lane >= s) incl += o; }
  __shared__ int wsum[4];
  if (lane == 63) wsum[wv] = incl;
  __syncthreads();
  int base = 0;
  for (int w2 = 0; w2 < wv; w2++) base += wsum[w2];
  if (t < NBLK) bpre[t] = base + incl - d;
}

__global__ __launch_bounds__(256) void k_scan3c(const int* __restrict__ deg,
                                                const int* __restrict__ bpre,
                                                int* __restrict__ off,
                                                int* __restrict__ cursor) {
  int t = threadIdx.x;
  int i = blockIdx.x * 256 + t;
  int d = (i < NNODES) ? deg[i] : 0;
  int lane = t & 63, wv = t >> 6;
  int incl = d;
  #pragma unroll
  for (int s = 1; s < 64; s <<= 1) { int o = __shfl_up(incl, s); if (lane >= s) incl += o; }
  __shared__ int wsum[4];
  if (lane == 63) wsum[wv] = incl;
  __syncthreads();
  int base = bpre[blockIdx.x];
  for (int w2 = 0; w2 < wv; w2++) base += wsum[w2];
  int ex = base + incl - d;
  if (i < NNODES) { off[i] = ex; cursor[i] = ex; }
  if (i == 0) off[NNODES] = NEDGE;
}

__global__ __launch_bounds__(256) void k_scatter(const int* __restrict__ ei,
                                                 int* __restrict__ cursor,
                                                 int* __restrict__ srcs) {
  int e = blockIdx.x * 256 + threadIdx.x;
  if (e >= NEDGE) return;
  int src = ei[e];
  int dst = ei[NEDGE + e];
  int pos = atomicAdd(&cursor[dst], 1);
  srcs[pos] = src;
}

// ------- Fused scores + aggregation: 1 wave per dst node -------------------
__global__ __launch_bounds__(256) void k_fused(const unsigned short* __restrict__ qkv,
                                               const int* __restrict__ off,
                                               const int* __restrict__ srcs,
                                               unsigned* __restrict__ U,
                                               float* __restrict__ hpart) {
  const int wave = threadIdx.x >> 6;
  const int lane = threadIdx.x & 63;
  const int n = blockIdx.x * 4 + wave;
  const int g   = lane >> 4;   // edge sub-group 0..3
  const int c16 = lane & 15;   // channel group (8 channels)

  uint4 qv = *(const uint4*)(qkv + (size_t)n * 384 + c16 * 8);
  float q0 = bflo(qv.x), q1 = bfhi(qv.x), q2 = bflo(qv.y), q3 = bfhi(qv.y);
  float q4 = bflo(qv.z), q5 = bfhi(qv.z), q6 = bflo(qv.w), q7 = bfhi(qv.w);

  float a0 = 0.f, a1 = 0.f, a2 = 0.f, a3 = 0.f, a4 = 0.f, a5 = 0.f, a6 = 0.f, a7 = 0.f;
  float lsum = 0.f;
  int i0 = off[n], i1 = off[n + 1];
  for (int i = i0; i < i1; i += 64) {
    int s_l = (i + lane < i1) ? srcs[i + lane] : 0;
    int cnt = i1 - i; if (cnt > 64) cnt = 64;
    for (int j = 0; j < cnt; j += 4) {
      int src = __shfl(s_l, j + g);
      bool valid = (j + g < cnt);
      const unsigned short* kr = qkv + (size_t)src * 384 + 128 + c16 * 8;
      uint4 kv = *(const uint4*)kr;
      uint4 vv = *(const uint4*)(kr + 128);
      float p = q0 * bflo(kv.x) + q1 * bfhi(kv.x) + q2 * bflo(kv.y) + q3 * bfhi(kv.y)
              + q4 * bflo(kv.z) + q5 * bfhi(kv.z) + q6 * bflo(kv.w) + q7 * bfhi(kv.w);
      p += __shfl_xor(p, 1);                  // pair within head
      float w = valid ? __expf(p * 0.25f) : 0.f;
      lsum += w;
      a0 += w * bflo(vv.x); a1 += w * bfhi(vv.x);
      a2 += w * bflo(vv.y); a3 += w * bfhi(vv.y);
      a4 += w * bflo(vv.z); a5 += w * bfhi(vv.z);
      a6 += w * bflo(vv.w); a7 += w * bfhi(vv.w);
    }
  }
  #pragma unroll
  for (int d = 16; d < 64; d <<= 1) {
    a0 += __shfl_xor(a0, d); a1 += __shfl_xor(a1, d);
    a2 += __shfl_xor(a2, d); a3 += __shfl_xor(a3, d);
    a4 += __shfl_xor(a4, d); a5 += __shfl_xor(a5, d);
    a6 += __shfl_xor(a6, d); a7 += __shfl_xor(a7, d);
    lsum += __shfl_xor(lsum, d);
  }
  __shared__ float wsum[4][8];
  if (lane < 16) {
    if ((c16 & 1) == 0) wsum[wave][c16 >> 1] = lsum;
    uint4 o;
    o.x = ((unsigned)f2bf(a1) << 16) | f2bf(a0);
    o.y = ((unsigned)f2bf(a3) << 16) | f2bf(a2);
    o.z = ((unsigned)f2bf(a5) << 16) | f2bf(a4);
    o.w = ((unsigned)f2bf(a7) << 16) | f2bf(a6);
    *(uint4*)(U + (size_t)n * 64 + c16 * 4) = o;
  }
  __syncthreads();
  if (threadIdx.x < 8) {
    hpart[blockIdx.x * 8 + threadIdx.x] =
        wsum[0][threadIdx.x] + wsum[1][threadIdx.x] + wsum[2][threadIdx.x] + wsum[3][threadIdx.x];
  }
}

// ---- Stage-1 denominator reduce: hpart[10000][8] -> dpart[40][8] ----------
__global__ __launch_bounds__(256) void k_reduce_part(const float* __restrict__ hpart,
                                                     float* __restrict__ dpart) {
  const int t = threadIdx.x;
  const int h = t & 7;
  const int r0 = blockIdx.x * (FBLK / RBLK);
  float s = 0.f;
  for (int r = r0 + (t >> 3); r < r0 + FBLK / RBLK; r += 32) s += hpart[r * 8 + h];
  #pragma unroll
  for (int d = 8; d < 64; d <<= 1) s += __shfl_xor(s, d);
  __shared__ float ws4[4][8];
  int lane = t & 63, wv = t >> 6;
  if (lane < 8) ws4[wv][lane] = s;
  __syncthreads();
  if (t < 8) dpart[blockIdx.x * 8 + t] = ws4[0][t] + ws4[1][t] + ws4[2][t] + ws4[3][t];
}

// ---- Scale U by 1/denom[head] (computes denom from dpart per block) -------
__global__ __launch_bounds__(256) void k_scale(unsigned* __restrict__ U,
                                               const float* __restrict__ dpart) {
  __shared__ float sinv[8];
  if (threadIdx.x < 64) {
    int h = threadIdx.x & 7;
    float s = 0.f;
    for (int r = threadIdx.x >> 3; r < RBLK; r += 8) s += dpart[r * 8 + h];
    #pragma unroll
    for (int d = 8; d < 64; d <<= 1) s += __shfl_xor(s, d);
    if (threadIdx.x < 8) sinv[h] = 1.0f / s;
  }
  __syncthreads();
  const int total = NNODES * 64;
  for (int i = blockIdx.x * 256 + threadIdx.x; i < total; i += 2048 * 256) {
    unsigned u = U[i];
    float s = sinv[(i & 63) >> 3];
    U[i] = ((unsigned)f2bf(bfhi(u) * s) << 16) | f2bf(bflo(u) * s);
  }
}

extern "C" void kernel_launch(void* const* d_in, const int* in_sizes, int n_in,
                              void* d_out, int out_size, void* d_ws, size_t ws_size,
                              hipStream_t stream) {
  const float* x    = (const float*)d_in[0];
  const int*   ei   = (const int*)d_in[1];
  const float* Wq   = (const float*)d_in[2];
  const float* bq   = (const float*)d_in[3];
  const float* Wk   = (const float*)d_in[4];
  const float* bk   = (const float*)d_in[5];
  const float* Wv   = (const float*)d_in[6];
  const float* bv   = (const float*)d_in[7];
  const float* Wo   = (const float*)d_in[8];
  const float* bo   = (const float*)d_in[9];
  const float* ln1g = (const float*)d_in[10];
  const float* ln1b = (const float*)d_in[11];
  const float* ln2g = (const float*)d_in[12];
  const float* ln2b = (const float*)d_in[13];
  const float* W1   = (const float*)d_in[14];
  const float* b1   = (const float*)d_in[15];
  const float* W2   = (const float*)d_in[16];
  const float* b2   = (const float*)d_in[17];
  float* out = (float*)d_out;

  char* base = (char*)d_ws;
  const size_t NCb = (size_t)NNODES * CCH * 2;                 // 10.24 MB
  unsigned short* xn   = (unsigned short*)(base);              // 10.24 MB; later xn2
  unsigned short* qkv  = (unsigned short*)(base + NCb);        // [N][384] 30.72 MB
  unsigned short* agg  = (unsigned short*)(base + 4 * NCb);    // U [N][128] 10.24 MB
  float*          x1   = (float*)(base + 5 * NCb);             // 20.48 MB
  unsigned short* ffn1 = qkv;                                  // overlays qkv+agg (40.96 MB)
  char* aux = base + 5 * NCb + (size_t)NNODES * CCH * 4;
  int* deg    = (int*)aux;                     aux += (size_t)NNODES * 4 + 256;
  int* off    = (int*)aux;                     aux += (size_t)(NNODES + 1) * 4 + 256;
  int* cursor = (int*)aux;                     aux += (size_t)NNODES * 4 + 256;
  int* srcs   = (int*)aux;                     aux += (size_t)NEDGE * 4;
  int* bsum   = (int*)aux;                     aux += 256 * 4;
  int* bpre   = (int*)aux;                     aux += 256 * 4;
  float* hpart = (float*)aux;                  aux += (size_t)FBLK * 8 * 4;
  float* dpart = (float*)aux;                  aux += (size_t)RBLK * 8 * 4 + 256;
  float* bqkv  = (float*)aux;                  aux += 384 * 4 + 256;
  unsigned short* Wqkvt = (unsigned short*)aux; aux += (size_t)384 * CCH * 2;
  unsigned short* Wot  = (unsigned short*)aux; aux += (size_t)CCH * CCH * 2;
  unsigned short* W1t  = (unsigned short*)aux; aux += (size_t)CCH * 4 * CCH * 2;
  unsigned short* W2t  = (unsigned short*)aux; aux += (size_t)CCH * 4 * CCH * 2;
  unsigned short* xn2 = xn;

  dim3 blk(256);
  dim3 gLN(NNODES / 4);
  dim3 gM(NNODES / 64, 1);
  dim3 gM3(NNODES / 64, 3);
  dim3 gM4(NNODES / 64, 4);
  dim3 gE((NEDGE + 255) / 256);
  dim3 gW64((CCH * CCH + 255) / 256);
  dim3 gW256((CCH * 4 * CCH + 255) / 256);

  // CSR build (depends only on ei)
  hipMemsetAsync(deg, 0, (size_t)NNODES * 4, stream);
  k_hist<<<gE, blk, 0, stream>>>(ei, deg);
  k_scan3a<<<NBLK, blk, 0, stream>>>(deg, bsum);
  k_scan3b<<<1, blk, 0, stream>>>(bsum, bpre);
  k_scan3c<<<NBLK, blk, 0, stream>>>(deg, bpre, off, cursor);
  k_scatter<<<gE, blk, 0, stream>>>(ei, cursor, srcs);

  // weight prep: Wqkv_t = [Wq^T | Wk^T | Wv^T] rows, bf16
  k_wprep<<<gW64, blk, 0, stream>>>(Wq, Wqkvt, CCH, CCH);
  k_wprep<<<gW64, blk, 0, stream>>>(Wk, Wqkvt + (size_t)CCH * CCH, CCH, CCH);
  k_wprep<<<gW64, blk, 0, stream>>>(Wv, Wqkvt + (size_t)2 * CCH * CCH, CCH, CCH);
  k_wprep<<<gW64, blk, 0, stream>>>(Wo, Wot, CCH, CCH);
  k_wprep<<<gW256, blk, 0, stream>>>(W1, W1t, CCH, 4 * CCH);
  k_wprep<<<gW256, blk, 0, stream>>>(W2, W2t, 4 * CCH, CCH);
  k_bcat<<<2, blk, 0, stream>>>(bq, bk, bv, bqkv);

  // LN1 + packed QKV GEMM
  k_ln_bf<<<gLN, blk, 0, stream>>>(x, ln1g, ln1b, (unsigned*)xn);
  k_mgemm<false, false, true><<<gM3, blk, 0, stream>>>(xn, Wqkvt, bqkv, nullptr, qkv, CCH, 384);

  // fused scores + aggregation (unnormalized) + denominator partials
  k_fused<<<FBLK, blk, 0, stream>>>(qkv, off, srcs, (unsigned*)agg, hpart);
  k_reduce_part<<<RBLK, blk, 0, stream>>>(hpart, dpart);
  k_scale<<<2048, blk, 0, stream>>>((unsigned*)agg, dpart);

  // out-proj + residual -> x1 (fp32)
  k_mgemm<false, true, false><<<gM, blk, 0, stream>>>(agg, Wot, bo, x, x1, CCH, CCH);
  // LN2 -> xn2 (overlays xn)
  k_ln_bf<<<gLN, blk, 0, stream>>>(x1, ln2g, ln2b, (unsigned*)xn2);
  // FFN1 (relu, bf16 out, overlays qkv+agg)
  k_mgemm<true, false, true><<<gM4, blk, 0, stream>>>(xn2, W1t, b1, nullptr, ffn1, CCH, 4 * CCH);
  // FFN2 (+residual x1) -> d_out fp32
  k_mgemm<false, true, false><<<gM, blk, 0, stream>>>(ffn1, W2t, b2, x1, out, 4 * CCH, CCH);
}

// Round 7
// 207.556 us; speedup vs baseline: 1.4373x; 1.0869x over previous
//
#include <hip/hip_runtime.h>
#include <math.h>

#define NNODES 40000
#define CCH    128
#define NH     8
#define HD     16
#define NEDGE  640000
#define NBLK   157    // ceil(NNODES/256)
#define FBLK   10000  // k_fused blocks (4 waves each -> 40000 nodes)
#define RBLK   40     // k_reduce_part blocks

typedef __attribute__((ext_vector_type(8))) short bf16x8;
typedef __attribute__((ext_vector_type(4))) float f32x4;
typedef __attribute__((ext_vector_type(2))) float f32x2;

__device__ inline unsigned short f2bf(float f) {
  union { float f; unsigned u; } c; c.f = f;
  unsigned r = c.u + 0x7fffu + ((c.u >> 16) & 1u);
  return (unsigned short)(r >> 16);
}
__device__ inline float bflo(unsigned u) { union { unsigned i; float f; } c; c.i = u << 16; return c.f; }
__device__ inline float bfhi(unsigned u) { union { unsigned i; float f; } c; c.i = u & 0xffff0000u; return c.f; }

// ---- fp8 e4m3 (OCP) helpers ----
__device__ inline unsigned char f2fp8(float v) {
#if __has_builtin(__builtin_amdgcn_cvt_pk_fp8_f32)
  return (unsigned char)(__builtin_amdgcn_cvt_pk_fp8_f32(v, v, 0, false) & 0xff);
#else
  union { float f; unsigned u; } c; c.f = v;
  unsigned s = (c.u >> 24) & 0x80;
  int e = (int)((c.u >> 23) & 0xff) - 127;
  unsigned m = c.u & 0x7fffff;
  if (e > 8) return s | 0x7e;
  if (e >= -6) {
    unsigned q = (m + 0x80000) >> 20; unsigned ee = e + 7;
    if (q == 8) { q = 0; ee++; }
    if (ee > 15) return s | 0x7e;
    return s | (ee << 3) | q;
  }
  if (e < -10) return (unsigned char)s;
  float a = fabsf(v); unsigned q = (unsigned)(a * 512.f + 0.5f); if (q > 7) q = 7;
  return s | q;
#endif
}
__device__ inline void fp8x4d(unsigned w, float* o) {
#if __has_builtin(__builtin_amdgcn_cvt_pk_f32_fp8)
  f32x2 lo = __builtin_amdgcn_cvt_pk_f32_fp8((int)w, false);
  f32x2 hi = __builtin_amdgcn_cvt_pk_f32_fp8((int)w, true);
  o[0] = lo[0]; o[1] = lo[1]; o[2] = hi[0]; o[3] = hi[1];
#else
  #pragma unroll
  for (int i = 0; i < 4; i++) {
    unsigned b = (w >> (8 * i)) & 0xff;
    unsigned s = b >> 7, e = (b >> 3) & 15, m = b & 7;
    float v;
    if (e) { union { unsigned u; float f; } c; c.u = ((e + 120) << 23) | (m << 20); v = c.f; }
    else v = m * (1.f / 512.f);
    o[i] = s ? -v : v;
  }
#endif
}

// ---------------- LayerNorm: 4 waves/block, 1 row/wave, bf16 out ----------
__global__ __launch_bounds__(256) void k_ln_bf(const float* __restrict__ x,
                                               const float* __restrict__ g,
                                               const float* __restrict__ b,
                                               unsigned* __restrict__ out) {
  int wave = threadIdx.x >> 6;
  int lane = threadIdx.x & 63;
  int row  = blockIdx.x * 4 + wave;
  if (row >= NNODES) return;
  const float2* xr = (const float2*)(x + (size_t)row * CCH);
  float2 v = xr[lane];
  float s  = v.x + v.y;
  float ss = v.x * v.x + v.y * v.y;
  #pragma unroll
  for (int d = 1; d < 64; d <<= 1) {
    s  += __shfl_xor(s, d);
    ss += __shfl_xor(ss, d);
  }
  float mean = s * (1.0f / CCH);
  float var  = ss * (1.0f / CCH) - mean * mean;
  float rstd = rsqrtf(var + 1e-5f);
  float2 gg = ((const float2*)g)[lane];
  float2 bb = ((const float2*)b)[lane];
  float ox = (v.x - mean) * rstd * gg.x + bb.x;
  float oy = (v.y - mean) * rstd * gg.y + bb.y;
  out[(size_t)row * 64 + lane] = ((unsigned)f2bf(oy) << 16) | f2bf(ox);
}

// ---------------- Weight prep: transpose + bf16 convert -------------------
__global__ __launch_bounds__(256) void k_wprep(const float* __restrict__ W,
                                               unsigned short* __restrict__ Wt,
                                               int K, int Nc) {
  int idx = blockIdx.x * 256 + threadIdx.x;
  if (idx >= K * Nc) return;
  int n = idx / K, k = idx - n * K;
  Wt[idx] = f2bf(W[(size_t)k * Nc + n]);
}

// Wo prep with per-row (channel) softmax-inv scaling
__global__ __launch_bounds__(256) void k_wprep_wo(const float* __restrict__ W,
                                                  const float* __restrict__ inv,
                                                  unsigned short* __restrict__ Wt) {
  int idx = blockIdx.x * 256 + threadIdx.x;
  if (idx >= CCH * CCH) return;
  int n = idx >> 7, k = idx & 127;
  Wt[idx] = f2bf(W[(size_t)k * CCH + n] * inv[k >> 4]);
}

__global__ __launch_bounds__(256) void k_bcat(const float* __restrict__ bq,
                                              const float* __restrict__ bk,
                                              const float* __restrict__ bv,
                                              float* __restrict__ bqkv) {
  int t = threadIdx.x + blockIdx.x * 256;
  if (t < 128)      bqkv[t] = bq[t];
  else if (t < 256) bqkv[t] = bk[t - 128];
  else if (t < 384) bqkv[t] = bv[t - 256];
}

// ------ MFMA GEMM. MODE: 0=f32 out, 1=bf16 out, 2=qkv-packed (512B rows) --
template <bool RELU, bool RES, int MODE>
__global__ __launch_bounds__(256) void k_mgemm(const unsigned short* __restrict__ A,
                                               const unsigned short* __restrict__ Bt,
                                               const float* __restrict__ bias,
                                               const float* __restrict__ res,
                                               void* __restrict__ outp,
                                               int K, int Nc) {
  __shared__ unsigned short As[64 * 64];
  __shared__ unsigned short Bs[128 * 64];
  const int tid  = threadIdx.x;
  const int row0 = blockIdx.x * 64;
  const int c0   = blockIdx.y * 128;
  const int l    = tid & 63;
  const int w    = tid >> 6;
  const int wr   = w >> 1;
  const int wc   = w & 1;

  f32x4 acc[2][4] = {};

  for (int kc = 0; kc < K; kc += 64) {
    __syncthreads();
    #pragma unroll
    for (int it = 0; it < 2; it++) {
      int idx = it * 256 + tid;
      int r = idx >> 3, s = idx & 7;
      uint4 vv = *(const uint4*)(A + (size_t)(row0 + r) * K + kc + s * 8);
      *(uint4*)(As + r * 64 + ((s ^ (r & 7)) * 8)) = vv;
    }
    #pragma unroll
    for (int it = 0; it < 4; it++) {
      int idx = it * 256 + tid;
      int n = idx >> 3, s = idx & 7;
      uint4 vv = *(const uint4*)(Bt + (size_t)(c0 + n) * K + kc + s * 8);
      *(uint4*)(Bs + n * 64 + ((s ^ (n & 7)) * 8)) = vv;
    }
    __syncthreads();
    #pragma unroll
    for (int kk = 0; kk < 2; kk++) {
      int sb = kk * 4 + (l >> 4);
      bf16x8 af[2], bfr[4];
      #pragma unroll
      for (int mi = 0; mi < 2; mi++) {
        int r = wr * 32 + mi * 16 + (l & 15);
        af[mi] = *(const bf16x8*)(As + r * 64 + ((sb ^ (r & 7)) * 8));
      }
      #pragma unroll
      for (int ni = 0; ni < 4; ni++) {
        int n = wc * 64 + ni * 16 + (l & 15);
        bfr[ni] = *(const bf16x8*)(Bs + n * 64 + ((sb ^ (n & 7)) * 8));
      }
      #pragma unroll
      for (int mi = 0; mi < 2; mi++)
        #pragma unroll
        for (int ni = 0; ni < 4; ni++)
          acc[mi][ni] = __builtin_amdgcn_mfma_f32_16x16x32_bf16(af[mi], bfr[ni], acc[mi][ni], 0, 0, 0);
    }
  }

  #pragma unroll
  for (int mi = 0; mi < 2; mi++) {
    #pragma unroll
    for (int p = 0; p < 4; p++) {
      int r = row0 + wr * 32 + mi * 16 + (l >> 4) * 4 + p;
      #pragma unroll
      for (int ni = 0; ni < 4; ni++) {
        int c = c0 + wc * 64 + ni * 16 + (l & 15);
        float val = acc[mi][ni][p] + bias[c];
        if (RES)  val += res[(size_t)r * Nc + c];
        if (RELU) val = fmaxf(val, 0.f);
        if (MODE == 0)      ((float*)outp)[(size_t)r * Nc + c] = val;
        else if (MODE == 1) ((unsigned short*)outp)[(size_t)r * Nc + c] = f2bf(val);
        else {
          char* rowb = (char*)outp + (size_t)r * 512;
          if (c < 128) *(unsigned short*)(rowb + c * 2) = f2bf(val);
          else         *(unsigned char*)(rowb + 256 + (c - 128)) = f2fp8(val);
        }
      }
    }
  }
}

// ---------------- CSR build: histogram -> 3-stage scan -> scatter ----------
__global__ __launch_bounds__(256) void k_hist(const int* __restrict__ ei,
                                              int* __restrict__ deg) {
  int e = blockIdx.x * 256 + threadIdx.x;
  if (e >= NEDGE) return;
  atomicAdd(&deg[ei[NEDGE + e]], 1);
}

__global__ __launch_bounds__(256) void k_scan3a(const int* __restrict__ deg,
                                                int* __restrict__ bsum) {
  int i = blockIdx.x * 256 + threadIdx.x;
  int d = (i < NNODES) ? deg[i] : 0;
  #pragma unroll
  for (int s = 1; s < 64; s <<= 1) d += __shfl_xor(d, s);
  __shared__ int ws4[4];
  if ((threadIdx.x & 63) == 0) ws4[threadIdx.x >> 6] = d;
  __syncthreads();
  if (threadIdx.x == 0) bsum[blockIdx.x] = ws4[0] + ws4[1] + ws4[2] + ws4[3];
}

__global__ __launch_bounds__(256) void k_scan3b(const int* __restrict__ bsum,
                                                int* __restrict__ bpre) {
  int t = threadIdx.x;
  int d = (t < NBLK) ? bsum[t] : 0;
  int lane = t & 63, wv = t >> 6;
  int incl = d;
  #pragma unroll
  for (int s = 1; s < 64; s <<= 1) { int o = __shfl_up(incl, s); if (lane >= s) incl += o; }
  __shared__ int wsum[4];
  if (lane == 63) wsum[wv] = incl;
  __syncthreads();
  int base = 0;
  for (int w2 = 0; w2 < wv; w2++) base += wsum[w2];
  if (t < NBLK) bpre[t] = base + incl - d;
}

__global__ __launch_bounds__(256) void k_scan3c(const int* __restrict__ deg,
                                                const int* __restrict__ bpre,
                                                int* __restrict__ off,
                                                int* __restrict__ cursor) {
  int t = threadIdx.x;
  int i = blockIdx.x * 256 + t;
  int d = (i < NNODES) ? deg[i] : 0;
  int lane = t & 63, wv = t >> 6;
  int incl = d;
  #pragma unroll
  for (int s = 1; s < 64; s <<= 1) { int o = __shfl_up(incl, s); if (lane >= s) incl += o; }
  __shared__ int wsum[4];
  if (lane == 63) wsum[wv] = incl;
  __syncthreads();
  int base = bpre[blockIdx.x];
  for (int w2 = 0; w2 < wv; w2++) base += wsum[w2];
  int ex = base + incl - d;
  if (i < NNODES) { off[i] = ex; cursor[i] = ex; }
  if (i == 0) off[NNODES] = NEDGE;
}

__global__ __launch_bounds__(256) void k_scatter(const int* __restrict__ ei,
                                                 int* __restrict__ cursor,
                                                 int* __restrict__ srcs) {
  int e = blockIdx.x * 256 + threadIdx.x;
  if (e >= NEDGE) return;
  int src = ei[e];
  int dst = ei[NEDGE + e];
  int pos = atomicAdd(&cursor[dst], 1);
  srcs[pos] = src;
}

// ------- Fused scores + aggregation: 1 wave/node, 1 lane = 1 (edge,head) ---
// qkv row (512B): [0,256) q bf16 x128; [256,384) k fp8 x128; [384,512) v fp8.
__global__ __launch_bounds__(256) void k_fused(const unsigned char* __restrict__ qkv,
                                               const int* __restrict__ off,
                                               const int* __restrict__ srcs,
                                               unsigned* __restrict__ U,
                                               float* __restrict__ hpart) {
  const int wave = threadIdx.x >> 6;
  const int lane = threadIdx.x & 63;
  const int n  = blockIdx.x * 4 + wave;
  const int g  = lane >> 3;   // edge slot 0..7
  const int c8 = lane & 7;    // head; channels c8*16 .. +15

  const uint4* qp = (const uint4*)(qkv + (size_t)n * 512 + c8 * 32);
  uint4 qa = qp[0], qb = qp[1];
  float qf[16];
  qf[0]=bflo(qa.x);  qf[1]=bfhi(qa.x);  qf[2]=bflo(qa.y);  qf[3]=bfhi(qa.y);
  qf[4]=bflo(qa.z);  qf[5]=bfhi(qa.z);  qf[6]=bflo(qa.w);  qf[7]=bfhi(qa.w);
  qf[8]=bflo(qb.x);  qf[9]=bfhi(qb.x);  qf[10]=bflo(qb.y); qf[11]=bfhi(qb.y);
  qf[12]=bflo(qb.z); qf[13]=bfhi(qb.z); qf[14]=bflo(qb.w); qf[15]=bfhi(qb.w);

  float acc[16];
  #pragma unroll
  for (int i = 0; i < 16; i++) acc[i] = 0.f;
  float lsum = 0.f;

  const int i0 = off[n], i1 = off[n + 1];
  for (int jb = i0; jb < i1; jb += 8) {
    int j = jb + g;
    bool valid = j < i1;
    int src = srcs[valid ? j : jb];
    const uint4* kp = (const uint4*)(qkv + (size_t)src * 512 + 256 + c8 * 16);
    uint4 kw = kp[0];
    uint4 vw = kp[8];      // +128 B -> v row
    float kf[16], vf[16];
    fp8x4d(kw.x, kf + 0); fp8x4d(kw.y, kf + 4); fp8x4d(kw.z, kf + 8); fp8x4d(kw.w, kf + 12);
    fp8x4d(vw.x, vf + 0); fp8x4d(vw.y, vf + 4); fp8x4d(vw.z, vf + 8); fp8x4d(vw.w, vf + 12);
    float p = 0.f;
    #pragma unroll
    for (int i = 0; i < 16; i++) p += qf[i] * kf[i];
    float w = valid ? __expf(p * 0.25f) : 0.f;
    lsum += w;
    #pragma unroll
    for (int i = 0; i < 16; i++) acc[i] += w * vf[i];
  }

  #pragma unroll
  for (int d = 8; d < 64; d <<= 1) {
    #pragma unroll
    for (int i = 0; i < 16; i++) acc[i] += __shfl_xor(acc[i], d);
    lsum += __shfl_xor(lsum, d);
  }

  __shared__ float wsum[4][8];
  if (lane < 8) {
    wsum[wave][c8] = lsum;
    unsigned o[8];
    #pragma unroll
    for (int i = 0; i < 8; i++)
      o[i] = ((unsigned)f2bf(acc[2 * i + 1]) << 16) | f2bf(acc[2 * i]);
    uint4* up = (uint4*)(U + (size_t)n * 64 + c8 * 8);
    up[0] = make_uint4(o[0], o[1], o[2], o[3]);
    up[1] = make_uint4(o[4], o[5], o[6], o[7]);
  }
  __syncthreads();
  if (threadIdx.x < 8) {
    hpart[blockIdx.x * 8 + threadIdx.x] =
        wsum[0][threadIdx.x] + wsum[1][threadIdx.x] + wsum[2][threadIdx.x] + wsum[3][threadIdx.x];
  }
}

// ---- Stage-1 denominator reduce: hpart[10000][8] -> dpart[40][8] ----------
__global__ __launch_bounds__(256) void k_reduce_part(const float* __restrict__ hpart,
                                                     float* __restrict__ dpart) {
  const int t = threadIdx.x;
  const int h = t & 7;
  const int r0 = blockIdx.x * (FBLK / RBLK);
  float s = 0.f;
  for (int r = r0 + (t >> 3); r < r0 + FBLK / RBLK; r += 32) s += hpart[r * 8 + h];
  #pragma unroll
  for (int d = 8; d < 64; d <<= 1) s += __shfl_xor(s, d);
  __shared__ float ws4[4][8];
  int lane = t & 63, wv = t >> 6;
  if (lane < 8) ws4[wv][lane] = s;
  __syncthreads();
  if (t < 8) dpart[blockIdx.x * 8 + t] = ws4[0][t] + ws4[1][t] + ws4[2][t] + ws4[3][t];
}

// ---- Final: dpart[40][8] -> inv[8] ---------------------------------------
__global__ __launch_bounds__(64) void k_inv(const float* __restrict__ dpart,
                                            float* __restrict__ inv) {
  int t = threadIdx.x;
  int h = t & 7;
  float s = 0.f;
  for (int r = t >> 3; r < RBLK; r += 8) s += dpart[r * 8 + h];
  #pragma unroll
  for (int d = 8; d < 64; d <<= 1) s += __shfl_xor(s, d);
  if (t < 8) inv[h] = 1.0f / s;
}

extern "C" void kernel_launch(void* const* d_in, const int* in_sizes, int n_in,
                              void* d_out, int out_size, void* d_ws, size_t ws_size,
                              hipStream_t stream) {
  const float* x    = (const float*)d_in[0];
  const int*   ei   = (const int*)d_in[1];
  const float* Wq   = (const float*)d_in[2];
  const float* bq   = (const float*)d_in[3];
  const float* Wk   = (const float*)d_in[4];
  const float* bk   = (const float*)d_in[5];
  const float* Wv   = (const float*)d_in[6];
  const float* bv   = (const float*)d_in[7];
  const float* Wo   = (const float*)d_in[8];
  const float* bo   = (const float*)d_in[9];
  const float* ln1g = (const float*)d_in[10];
  const float* ln1b = (const float*)d_in[11];
  const float* ln2g = (const float*)d_in[12];
  const float* ln2b = (const float*)d_in[13];
  const float* W1   = (const float*)d_in[14];
  const float* b1   = (const float*)d_in[15];
  const float* W2   = (const float*)d_in[16];
  const float* b2   = (const float*)d_in[17];
  float* out = (float*)d_out;

  char* p = (char*)d_ws;
  unsigned short* xn   = (unsigned short*)p; p += (size_t)NNODES * CCH * 2;   // 10.24 MB; reused as xn2
  unsigned char*  qkvb = (unsigned char*)p;  p += (size_t)NNODES * 512;       // 20.48 MB
  unsigned short* agg  = (unsigned short*)p; p += (size_t)NNODES * CCH * 2;   // U, 10.24 MB
  float*          x1   = (float*)p;          p += (size_t)NNODES * CCH * 4;   // 20.48 MB
  unsigned short* ffn1 = (unsigned short*)p; p += (size_t)NNODES * 4 * CCH * 2; // 40.96 MB
  int* deg    = (int*)p;                     p += (size_t)NNODES * 4 + 256;
  int* off    = (int*)p;                     p += (size_t)(NNODES + 1) * 4 + 256;
  int* cursor = (int*)p;                     p += (size_t)NNODES * 4 + 256;
  int* srcs   = (int*)p;                     p += (size_t)NEDGE * 4;
  int* bsum   = (int*)p;                     p += 256 * 4;
  int* bpre   = (int*)p;                     p += 256 * 4;
  float* hpart = (float*)p;                  p += (size_t)FBLK * 8 * 4;
  float* dpart = (float*)p;                  p += (size_t)RBLK * 8 * 4 + 256;
  float* inv   = (float*)p;                  p += 256;
  float* bqkv  = (float*)p;                  p += 384 * 4 + 256;
  unsigned short* Wqkvt = (unsigned short*)p; p += (size_t)384 * CCH * 2;
  unsigned short* Wot   = (unsigned short*)p; p += (size_t)CCH * CCH * 2;
  unsigned short* W1t   = (unsigned short*)p; p += (size_t)CCH * 4 * CCH * 2;
  unsigned short* W2t   = (unsigned short*)p; p += (size_t)CCH * 4 * CCH * 2;
  unsigned short* xn2 = xn;

  dim3 blk(256);
  dim3 gLN(NNODES / 4);
  dim3 gM(NNODES / 64, 1);
  dim3 gM3(NNODES / 64, 3);
  dim3 gM4(NNODES / 64, 4);
  dim3 gE((NEDGE + 255) / 256);
  dim3 gW64((CCH * CCH + 255) / 256);
  dim3 gW256((CCH * 4 * CCH + 255) / 256);

  // CSR build (depends only on ei)
  hipMemsetAsync(deg, 0, (size_t)NNODES * 4, stream);
  k_hist<<<gE, blk, 0, stream>>>(ei, deg);
  k_scan3a<<<NBLK, blk, 0, stream>>>(deg, bsum);
  k_scan3b<<<1, blk, 0, stream>>>(bsum, bpre);
  k_scan3c<<<NBLK, blk, 0, stream>>>(deg, bpre, off, cursor);
  k_scatter<<<gE, blk, 0, stream>>>(ei, cursor, srcs);

  // weight prep: Wqkv_t = [Wq^T | Wk^T | Wv^T] rows, bf16 (Wo deferred)
  k_wprep<<<gW64, blk, 0, stream>>>(Wq, Wqkvt, CCH, CCH);
  k_wprep<<<gW64, blk, 0, stream>>>(Wk, Wqkvt + (size_t)CCH * CCH, CCH, CCH);
  k_wprep<<<gW64, blk, 0, stream>>>(Wv, Wqkvt + (size_t)2 * CCH * CCH, CCH, CCH);
  k_wprep<<<gW256, blk, 0, stream>>>(W1, W1t, CCH, 4 * CCH);
  k_wprep<<<gW256, blk, 0, stream>>>(W2, W2t, 4 * CCH, CCH);
  k_bcat<<<2, blk, 0, stream>>>(bq, bk, bv, bqkv);

  // LN1 + packed QKV GEMM (q bf16 | k fp8 | v fp8, 512B rows)
  k_ln_bf<<<gLN, blk, 0, stream>>>(x, ln1g, ln1b, (unsigned*)xn);
  k_mgemm<false, false, 2><<<gM3, blk, 0, stream>>>(xn, Wqkvt, bqkv, nullptr, qkvb, CCH, 384);

  // fused scores + aggregation (unnormalized U) + denominator partials
  k_fused<<<FBLK, blk, 0, stream>>>(qkvb, off, srcs, (unsigned*)agg, hpart);
  k_reduce_part<<<RBLK, blk, 0, stream>>>(hpart, dpart);
  k_inv<<<1, dim3(64), 0, stream>>>(dpart, inv);

  // Wo prep with inv-scaled rows, then out-proj + residual -> x1 (fp32)
  k_wprep_wo<<<gW64, blk, 0, stream>>>(Wo, inv, Wot);
  k_mgemm<false, true, 0><<<gM, blk, 0, stream>>>(agg, Wot, bo, x, x1, CCH, CCH);

  // LN2 -> xn2 (overlays xn)
  k_ln_bf<<<gLN, blk, 0, stream>>>(x1, ln2g, ln2b, (unsigned*)xn2);
  // FFN1 (relu, bf16 out)
  k_mgemm<true, false, 1><<<gM4, blk, 0, stream>>>(xn2, W1t, b1, nullptr, ffn1, CCH, 4 * CCH);
  // FFN2 (+residual x1) -> d_out fp32
  k_mgemm<false, true, 0><<<gM, blk, 0, stream>>>(ffn1, W2t, b2, x1, out, 4 * CCH, CCH);
}

// Round 8
// 181.017 us; speedup vs baseline: 1.6480x; 1.1466x over previous
//
#include <hip/hip_runtime.h>
#include <math.h>

#define NNODES 40000
#define CCH    128
#define NH     8
#define HD     16
#define NEDGE  640000
#define NBLK   157    // ceil(NNODES/256)
#define FBLK   10000  // k_fused blocks (4 waves each -> 40000 nodes)
#define RBLK   40     // k_reduce_part blocks

typedef __attribute__((ext_vector_type(8))) short bf16x8;
typedef __attribute__((ext_vector_type(4))) float f32x4;
typedef __attribute__((ext_vector_type(2))) float f32x2;

__device__ inline unsigned short f2bf(float f) {
  union { float f; unsigned u; } c; c.f = f;
  unsigned r = c.u + 0x7fffu + ((c.u >> 16) & 1u);
  return (unsigned short)(r >> 16);
}
__device__ inline float bflo(unsigned u) { union { unsigned i; float f; } c; c.i = u << 16; return c.f; }
__device__ inline float bfhi(unsigned u) { union { unsigned i; float f; } c; c.i = u & 0xffff0000u; return c.f; }

// ---- fp8 e4m3 (OCP) helpers ----
__device__ inline unsigned char f2fp8(float v) {
#if __has_builtin(__builtin_amdgcn_cvt_pk_fp8_f32)
  return (unsigned char)(__builtin_amdgcn_cvt_pk_fp8_f32(v, v, 0, false) & 0xff);
#else
  union { float f; unsigned u; } c; c.f = v;
  unsigned s = (c.u >> 24) & 0x80;
  int e = (int)((c.u >> 23) & 0xff) - 127;
  unsigned m = c.u & 0x7fffff;
  if (e > 8) return s | 0x7e;
  if (e >= -6) {
    unsigned q = (m + 0x80000) >> 20; unsigned ee = e + 7;
    if (q == 8) { q = 0; ee++; }
    if (ee > 15) return s | 0x7e;
    return s | (ee << 3) | q;
  }
  if (e < -10) return (unsigned char)s;
  float a = fabsf(v); unsigned q = (unsigned)(a * 512.f + 0.5f); if (q > 7) q = 7;
  return s | q;
#endif
}
__device__ inline void fp8x4d(unsigned w, float* o) {
#if __has_builtin(__builtin_amdgcn_cvt_pk_f32_fp8)
  f32x2 lo = __builtin_amdgcn_cvt_pk_f32_fp8((int)w, false);
  f32x2 hi = __builtin_amdgcn_cvt_pk_f32_fp8((int)w, true);
  o[0] = lo[0]; o[1] = lo[1]; o[2] = hi[0]; o[3] = hi[1];
#else
  #pragma unroll
  for (int i = 0; i < 4; i++) {
    unsigned b = (w >> (8 * i)) & 0xff;
    unsigned s = b >> 7, e = (b >> 3) & 15, m = b & 7;
    float v;
    if (e) { union { unsigned u; float f; } c; c.u = ((e + 120) << 23) | (m << 20); v = c.f; }
    else v = m * (1.f / 512.f);
    o[i] = s ? -v : v;
  }
#endif
}

// ---------------- LayerNorm: 4 waves/block, 1 row/wave, bf16 out ----------
__global__ __launch_bounds__(256) void k_ln_bf(const float* __restrict__ x,
                                               const float* __restrict__ g,
                                               const float* __restrict__ b,
                                               unsigned* __restrict__ out) {
  int wave = threadIdx.x >> 6;
  int lane = threadIdx.x & 63;
  int row  = blockIdx.x * 4 + wave;
  if (row >= NNODES) return;
  const float2* xr = (const float2*)(x + (size_t)row * CCH);
  float2 v = xr[lane];
  float s  = v.x + v.y;
  float ss = v.x * v.x + v.y * v.y;
  #pragma unroll
  for (int d = 1; d < 64; d <<= 1) {
    s  += __shfl_xor(s, d);
    ss += __shfl_xor(ss, d);
  }
  float mean = s * (1.0f / CCH);
  float var  = ss * (1.0f / CCH) - mean * mean;
  float rstd = rsqrtf(var + 1e-5f);
  float2 gg = ((const float2*)g)[lane];
  float2 bb = ((const float2*)b)[lane];
  float ox = (v.x - mean) * rstd * gg.x + bb.x;
  float oy = (v.y - mean) * rstd * gg.y + bb.y;
  out[(size_t)row * 64 + lane] = ((unsigned)f2bf(oy) << 16) | f2bf(ox);
}

// ---------------- Weight prep: transpose + bf16 convert -------------------
__global__ __launch_bounds__(256) void k_wprep(const float* __restrict__ W,
                                               unsigned short* __restrict__ Wt,
                                               int K, int Nc) {
  int idx = blockIdx.x * 256 + threadIdx.x;
  if (idx >= K * Nc) return;
  int n = idx / K, k = idx - n * K;
  Wt[idx] = f2bf(W[(size_t)k * Nc + n]);
}

// Wo prep with per-row (channel) softmax-inv scaling
__global__ __launch_bounds__(256) void k_wprep_wo(const float* __restrict__ W,
                                                  const float* __restrict__ inv,
                                                  unsigned short* __restrict__ Wt) {
  int idx = blockIdx.x * 256 + threadIdx.x;
  if (idx >= CCH * CCH) return;
  int n = idx >> 7, k = idx & 127;
  Wt[idx] = f2bf(W[(size_t)k * CCH + n] * inv[k >> 4]);
}

__global__ __launch_bounds__(256) void k_bcat(const float* __restrict__ bq,
                                              const float* __restrict__ bk,
                                              const float* __restrict__ bv,
                                              float* __restrict__ bqkv) {
  int t = threadIdx.x + blockIdx.x * 256;
  if (t < 128)      bqkv[t] = bq[t];
  else if (t < 256) bqkv[t] = bk[t - 128];
  else if (t < 384) bqkv[t] = bv[t - 256];
}

// ------ MFMA GEMM. MODE: 0=f32 out, 1=bf16 out, 2=qkv-packed (512B rows) --
template <bool RELU, bool RES, int MODE>
__global__ __launch_bounds__(256) void k_mgemm(const unsigned short* __restrict__ A,
                                               const unsigned short* __restrict__ Bt,
                                               const float* __restrict__ bias,
                                               const float* __restrict__ res,
                                               void* __restrict__ outp,
                                               int K, int Nc) {
  __shared__ unsigned short As[64 * 64];
  __shared__ unsigned short Bs[128 * 64];
  const int tid  = threadIdx.x;
  const int row0 = blockIdx.x * 64;
  const int c0   = blockIdx.y * 128;
  const int l    = tid & 63;
  const int w    = tid >> 6;
  const int wr   = w >> 1;
  const int wc   = w & 1;

  f32x4 acc[2][4] = {};

  for (int kc = 0; kc < K; kc += 64) {
    __syncthreads();
    #pragma unroll
    for (int it = 0; it < 2; it++) {
      int idx = it * 256 + tid;
      int r = idx >> 3, s = idx & 7;
      uint4 vv = *(const uint4*)(A + (size_t)(row0 + r) * K + kc + s * 8);
      *(uint4*)(As + r * 64 + ((s ^ (r & 7)) * 8)) = vv;
    }
    #pragma unroll
    for (int it = 0; it < 4; it++) {
      int idx = it * 256 + tid;
      int n = idx >> 3, s = idx & 7;
      uint4 vv = *(const uint4*)(Bt + (size_t)(c0 + n) * K + kc + s * 8);
      *(uint4*)(Bs + n * 64 + ((s ^ (n & 7)) * 8)) = vv;
    }
    __syncthreads();
    #pragma unroll
    for (int kk = 0; kk < 2; kk++) {
      int sb = kk * 4 + (l >> 4);
      bf16x8 af[2], bfr[4];
      #pragma unroll
      for (int mi = 0; mi < 2; mi++) {
        int r = wr * 32 + mi * 16 + (l & 15);
        af[mi] = *(const bf16x8*)(As + r * 64 + ((sb ^ (r & 7)) * 8));
      }
      #pragma unroll
      for (int ni = 0; ni < 4; ni++) {
        int n = wc * 64 + ni * 16 + (l & 15);
        bfr[ni] = *(const bf16x8*)(Bs + n * 64 + ((sb ^ (n & 7)) * 8));
      }
      #pragma unroll
      for (int mi = 0; mi < 2; mi++)
        #pragma unroll
        for (int ni = 0; ni < 4; ni++)
          acc[mi][ni] = __builtin_amdgcn_mfma_f32_16x16x32_bf16(af[mi], bfr[ni], acc[mi][ni], 0, 0, 0);
    }
  }

  #pragma unroll
  for (int mi = 0; mi < 2; mi++) {
    #pragma unroll
    for (int p = 0; p < 4; p++) {
      int r = row0 + wr * 32 + mi * 16 + (l >> 4) * 4 + p;
      #pragma unroll
      for (int ni = 0; ni < 4; ni++) {
        int c = c0 + wc * 64 + ni * 16 + (l & 15);
        float val = acc[mi][ni][p] + bias[c];
        if (RES)  val += res[(size_t)r * Nc + c];
        if (RELU) val = fmaxf(val, 0.f);
        if (MODE == 0)      ((float*)outp)[(size_t)r * Nc + c] = val;
        else if (MODE == 1) ((unsigned short*)outp)[(size_t)r * Nc + c] = f2bf(val);
        else {
          char* rowb = (char*)outp + (size_t)r * 512;
          if (c < 128) *(unsigned short*)(rowb + c * 2) = f2bf(val);
          else         *(unsigned char*)(rowb + 256 + (c - 128)) = f2fp8(val);
        }
      }
    }
  }
}

// ------- CSR build: histogram+rank -> 3-stage scan -> atomic-free scatter --
__global__ __launch_bounds__(256) void k_histrank(const int* __restrict__ ei,
                                                  int* __restrict__ deg,
                                                  int* __restrict__ rank) {
  int e = blockIdx.x * 256 + threadIdx.x;
  if (e >= NEDGE) return;
  rank[e] = atomicAdd(&deg[ei[NEDGE + e]], 1);
}

__global__ __launch_bounds__(256) void k_scan3a(const int* __restrict__ deg,
                                                int* __restrict__ bsum) {
  int i = blockIdx.x * 256 + threadIdx.x;
  int d = (i < NNODES) ? deg[i] : 0;
  #pragma unroll
  for (int s = 1; s < 64; s <<= 1) d += __shfl_xor(d, s);
  __shared__ int ws4[4];
  if ((threadIdx.x & 63) == 0) ws4[threadIdx.x >> 6] = d;
  __syncthreads();
  if (threadIdx.x == 0) bsum[blockIdx.x] = ws4[0] + ws4[1] + ws4[2] + ws4[3];
}

__global__ __launch_bounds__(256) void k_scan3b(const int* __restrict__ bsum,
                                                int* __restrict__ bpre) {
  int t = threadIdx.x;
  int d = (t < NBLK) ? bsum[t] : 0;
  int lane = t & 63, wv = t >> 6;
  int incl = d;
  #pragma unroll
  for (int s = 1; s < 64; s <<= 1) { int o = __shfl_up(incl, s); if (lane >= s) incl += o; }
  __shared__ int wsum[4];
  if (lane == 63) wsum[wv] = incl;
  __syncthreads();
  int base = 0;
  for (int w2 = 0; w2 < wv; w2++) base += wsum[w2];
  if (t < NBLK) bpre[t] = base + incl - d;
}

__global__ __launch_bounds__(256) void k_scan3c(const int* __restrict__ deg,
                                                const int* __restrict__ bpre,
                                                int* __restrict__ off) {
  int t = threadIdx.x;
  int i = blockIdx.x * 256 + t;
  int d = (i < NNODES) ? deg[i] : 0;
  int lane = t & 63, wv = t >> 6;
  int incl = d;
  #pragma unroll
  for (int s = 1; s < 64; s <<= 1) { int o = __shfl_up(incl, s); if (lane >= s) incl += o; }
  __shared__ int wsum[4];
  if (lane == 63) wsum[wv] = incl;
  __syncthreads();
  int base = bpre[blockIdx.x];
  for (int w2 = 0; w2 < wv; w2++) base += wsum[w2];
  int ex = base + incl - d;
  if (i < NNODES) off[i] = ex;
  if (i == 0) off[NNODES] = NEDGE;
}

__global__ __launch_bounds__(256) void k_scatter(const int* __restrict__ ei,
                                                 const int* __restrict__ off,
                                                 const int* __restrict__ rank,
                                                 int* __restrict__ srcs) {
  int e = blockIdx.x * 256 + threadIdx.x;
  if (e >= NEDGE) return;
  srcs[off[ei[NEDGE + e]] + rank[e]] = ei[e];
}

// ------- Fused scores + aggregation: 1 wave/node, 1 lane = 1 (edge,head) ---
// qkv row (512B): [0,256) q bf16 x128; [256,384) k fp8 x128; [384,512) v fp8.
__global__ __launch_bounds__(256) void k_fused(const unsigned char* __restrict__ qkv,
                                               const int* __restrict__ off,
                                               const int* __restrict__ srcs,
                                               unsigned* __restrict__ U,
                                               float* __restrict__ hpart) {
  const int wave = threadIdx.x >> 6;
  const int lane = threadIdx.x & 63;
  const int n  = blockIdx.x * 4 + wave;
  const int g  = lane >> 3;   // edge slot 0..7
  const int c8 = lane & 7;    // head; channels c8*16 .. +15

  const uint4* qp = (const uint4*)(qkv + (size_t)n * 512 + c8 * 32);
  uint4 qa = qp[0], qb = qp[1];
  float qf[16];
  qf[0]=bflo(qa.x);  qf[1]=bfhi(qa.x);  qf[2]=bflo(qa.y);  qf[3]=bfhi(qa.y);
  qf[4]=bflo(qa.z);  qf[5]=bfhi(qa.z);  qf[6]=bflo(qa.w);  qf[7]=bfhi(qa.w);
  qf[8]=bflo(qb.x);  qf[9]=bfhi(qb.x);  qf[10]=bflo(qb.y); qf[11]=bfhi(qb.y);
  qf[12]=bflo(qb.z); qf[13]=bfhi(qb.z); qf[14]=bflo(qb.w); qf[15]=bfhi(qb.w);

  float acc[16];
  #pragma unroll
  for (int i = 0; i < 16; i++) acc[i] = 0.f;
  float lsum = 0.f;

  const int i0 = off[n], i1 = off[n + 1];
  for (int jb = i0; jb < i1; jb += 8) {
    int j = jb + g;
    bool valid = j < i1;
    int src = srcs[valid ? j : jb];
    const uint4* kp = (const uint4*)(qkv + (size_t)src * 512 + 256 + c8 * 16);
    uint4 kw = kp[0];
    uint4 vw = kp[8];      // +128 B -> v row
    float kf[16], vf[16];
    fp8x4d(kw.x, kf + 0); fp8x4d(kw.y, kf + 4); fp8x4d(kw.z, kf + 8); fp8x4d(kw.w, kf + 12);
    fp8x4d(vw.x, vf + 0); fp8x4d(vw.y, vf + 4); fp8x4d(vw.z, vf + 8); fp8x4d(vw.w, vf + 12);
    float p = 0.f;
    #pragma unroll
    for (int i = 0; i < 16; i++) p += qf[i] * kf[i];
    float w = valid ? __expf(p * 0.25f) : 0.f;
    lsum += w;
    #pragma unroll
    for (int i = 0; i < 16; i++) acc[i] += w * vf[i];
  }

  #pragma unroll
  for (int d = 8; d < 64; d <<= 1) {
    #pragma unroll
    for (int i = 0; i < 16; i++) acc[i] += __shfl_xor(acc[i], d);
    lsum += __shfl_xor(lsum, d);
  }

  __shared__ float wsum[4][8];
  if (lane < 8) {
    wsum[wave][c8] = lsum;
    unsigned o[8];
    #pragma unroll
    for (int i = 0; i < 8; i++)
      o[i] = ((unsigned)f2bf(acc[2 * i + 1]) << 16) | f2bf(acc[2 * i]);
    uint4* up = (uint4*)(U + (size_t)n * 64 + c8 * 8);
    up[0] = make_uint4(o[0], o[1], o[2], o[3]);
    up[1] = make_uint4(o[4], o[5], o[6], o[7]);
  }
  __syncthreads();
  if (threadIdx.x < 8) {
    hpart[blockIdx.x * 8 + threadIdx.x] =
        wsum[0][threadIdx.x] + wsum[1][threadIdx.x] + wsum[2][threadIdx.x] + wsum[3][threadIdx.x];
  }
}

// ---- Stage-1 denominator reduce: hpart[10000][8] -> dpart[40][8] ----------
__global__ __launch_bounds__(256) void k_reduce_part(const float* __restrict__ hpart,
                                                     float* __restrict__ dpart) {
  const int t = threadIdx.x;
  const int h = t & 7;
  const int r0 = blockIdx.x * (FBLK / RBLK);
  float s = 0.f;
  for (int r = r0 + (t >> 3); r < r0 + FBLK / RBLK; r += 32) s += hpart[r * 8 + h];
  #pragma unroll
  for (int d = 8; d < 64; d <<= 1) s += __shfl_xor(s, d);
  __shared__ float ws4[4][8];
  int lane = t & 63, wv = t >> 6;
  if (lane < 8) ws4[wv][lane] = s;
  __syncthreads();
  if (t < 8) dpart[blockIdx.x * 8 + t] = ws4[0][t] + ws4[1][t] + ws4[2][t] + ws4[3][t];
}

// ---- Final: dpart[40][8] -> inv[8] ---------------------------------------
__global__ __launch_bounds__(64) void k_inv(const float* __restrict__ dpart,
                                            float* __restrict__ inv) {
  int t = threadIdx.x;
  int h = t & 7;
  float s = 0.f;
  for (int r = t >> 3; r < RBLK; r += 8) s += dpart[r * 8 + h];
  #pragma unroll
  for (int d = 8; d < 64; d <<= 1) s += __shfl_xor(s, d);
  if (t < 8) inv[h] = 1.0f / s;
}

extern "C" void kernel_launch(void* const* d_in, const int* in_sizes, int n_in,
                              void* d_out, int out_size, void* d_ws, size_t ws_size,
                              hipStream_t stream) {
  const float* x    = (const float*)d_in[0];
  const int*   ei   = (const int*)d_in[1];
  const float* Wq   = (const float*)d_in[2];
  const float* bq   = (const float*)d_in[3];
  const float* Wk   = (const float*)d_in[4];
  const float* bk   = (const float*)d_in[5];
  const float* Wv   = (const float*)d_in[6];
  const float* bv   = (const float*)d_in[7];
  const float* Wo   = (const float*)d_in[8];
  const float* bo   = (const float*)d_in[9];
  const float* ln1g = (const float*)d_in[10];
  const float* ln1b = (const float*)d_in[11];
  const float* ln2g = (const float*)d_in[12];
  const float* ln2b = (const float*)d_in[13];
  const float* W1   = (const float*)d_in[14];
  const float* b1   = (const float*)d_in[15];
  const float* W2   = (const float*)d_in[16];
  const float* b2   = (const float*)d_in[17];
  float* out = (float*)d_out;

  char* p = (char*)d_ws;
  unsigned short* xn   = (unsigned short*)p; p += (size_t)NNODES * CCH * 2;   // 10.24 MB; reused as xn2
  unsigned char*  qkvb = (unsigned char*)p;  p += (size_t)NNODES * 512;       // 20.48 MB
  unsigned short* agg  = (unsigned short*)p; p += (size_t)NNODES * CCH * 2;   // U, 10.24 MB
  float*          x1   = (float*)p;          p += (size_t)NNODES * CCH * 4;   // 20.48 MB
  unsigned short* ffn1 = (unsigned short*)p; p += (size_t)NNODES * 4 * CCH * 2; // 40.96 MB
  int* deg    = (int*)p;                     p += (size_t)NNODES * 4 + 256;
  int* off    = (int*)p;                     p += (size_t)(NNODES + 1) * 4 + 256;
  int* rank   = (int*)p;                     p += (size_t)NEDGE * 4;
  int* srcs   = (int*)p;                     p += (size_t)NEDGE * 4;
  int* bsum   = (int*)p;                     p += 256 * 4;
  int* bpre   = (int*)p;                     p += 256 * 4;
  float* hpart = (float*)p;                  p += (size_t)FBLK * 8 * 4;
  float* dpart = (float*)p;                  p += (size_t)RBLK * 8 * 4 + 256;
  float* inv   = (float*)p;                  p += 256;
  float* bqkv  = (float*)p;                  p += 384 * 4 + 256;
  unsigned short* Wqkvt = (unsigned short*)p; p += (size_t)384 * CCH * 2;
  unsigned short* Wot   = (unsigned short*)p; p += (size_t)CCH * CCH * 2;
  unsigned short* W1t   = (unsigned short*)p; p += (size_t)CCH * 4 * CCH * 2;
  unsigned short* W2t   = (unsigned short*)p; p += (size_t)CCH * 4 * CCH * 2;
  unsigned short* xn2 = xn;

  dim3 blk(256);
  dim3 gLN(NNODES / 4);
  dim3 gM(NNODES / 64, 1);
  dim3 gM3(NNODES / 64, 3);
  dim3 gM4(NNODES / 64, 4);
  dim3 gE((NEDGE + 255) / 256);
  dim3 gW64((CCH * CCH + 255) / 256);
  dim3 gW256((CCH * 4 * CCH + 255) / 256);

  // CSR build (depends only on ei): hist+rank -> scan -> atomic-free scatter
  hipMemsetAsync(deg, 0, (size_t)NNODES * 4, stream);
  k_histrank<<<gE, blk, 0, stream>>>(ei, deg, rank);
  k_scan3a<<<NBLK, blk, 0, stream>>>(deg, bsum);
  k_scan3b<<<1, blk, 0, stream>>>(bsum, bpre);
  k_scan3c<<<NBLK, blk, 0, stream>>>(deg, bpre, off);
  k_scatter<<<gE, blk, 0, stream>>>(ei, off, rank, srcs);

  // weight prep: Wqkv_t = [Wq^T | Wk^T | Wv^T] rows, bf16 (Wo deferred)
  k_wprep<<<gW64, blk, 0, stream>>>(Wq, Wqkvt, CCH, CCH);
  k_wprep<<<gW64, blk, 0, stream>>>(Wk, Wqkvt + (size_t)CCH * CCH, CCH, CCH);
  k_wprep<<<gW64, blk, 0, stream>>>(Wv, Wqkvt + (size_t)2 * CCH * CCH, CCH, CCH);
  k_wprep<<<gW256, blk, 0, stream>>>(W1, W1t, CCH, 4 * CCH);
  k_wprep<<<gW256, blk, 0, stream>>>(W2, W2t, 4 * CCH, CCH);
  k_bcat<<<2, blk, 0, stream>>>(bq, bk, bv, bqkv);

  // LN1 + packed QKV GEMM (q bf16 | k fp8 | v fp8, 512B rows)
  k_ln_bf<<<gLN, blk, 0, stream>>>(x, ln1g, ln1b, (unsigned*)xn);
  k_mgemm<false, false, 2><<<gM3, blk, 0, stream>>>(xn, Wqkvt, bqkv, nullptr, qkvb, CCH, 384);

  // fused scores + aggregation (unnormalized U) + denominator partials
  k_fused<<<FBLK, blk, 0, stream>>>(qkvb, off, srcs, (unsigned*)agg, hpart);
  k_reduce_part<<<RBLK, blk, 0, stream>>>(hpart, dpart);
  k_inv<<<1, dim3(64), 0, stream>>>(dpart, inv);

  // Wo prep with inv-scaled rows, then out-proj + residual -> x1 (fp32)
  k_wprep_wo<<<gW64, blk, 0, stream>>>(Wo, inv, Wot);
  k_mgemm<false, true, 0><<<gM, blk, 0, stream>>>(agg, Wot, bo, x, x1, CCH, CCH);

  // LN2 -> xn2 (overlays xn)
  k_ln_bf<<<gLN, blk, 0, stream>>>(x1, ln2g, ln2b, (unsigned*)xn2);
  // FFN1 (relu, bf16 out)
  k_mgemm<true, false, 1><<<gM4, blk, 0, stream>>>(xn2, W1t, b1, nullptr, ffn1, CCH, 4 * CCH);
  // FFN2 (+residual x1) -> d_out fp32
  k_mgemm<false, true, 0><<<gM, blk, 0, stream>>>(ffn1, W2t, b2, x1, out, 4 * CCH, CCH);
}